// Round 15
// baseline (116.788 us; speedup 1.0000x reference)
//
#include <hip/hip_runtime.h>
#include <math.h>

// Gumbel subset (relaxed top-k) — B=2048 rows, N=8192, K=64 softmax steps.
// Multiplicative reformulation: v_i = exp(s0_i - M0), per step:
//   w = v*rinv(S); kh += w; v = fma(-w, v, v); part' = sum(v).
// R15: occupancy push 3 -> 5 waves/SIMD by shrinking TOTAL reg footprint:
//  (1) kh in packed fp16: cvt_pkrtz(w0,w1) + v_pk_add_f16 (asm, R10/R11-
//      proven pure/early-clobber style) = 2 instr/pair, SAME op count as
//      the 2 f32 adds replaced; kh state 32 -> 16 regs. Numerics at R7's
//      proven 0.031 scale (v stays f32; only kh accumulation is fp16).
//  (2) two-pass prologue (R12-proven): pass 1 = max only (no s0[] staging
//      peak), pass 2 reloads a+b from L2/L3 (R12: FETCH stayed ~65MB).
//  (3) __launch_bounds__(256,5): cap 102 vs ~70 peak need (R13's spill was
//      cap 102 vs ~160 need; need is now genuinely under the cap).
// Inner math otherwise bit-identical to R14 (busy 82us, DPP reduce proven).

typedef _Float16 h2 __attribute__((ext_vector_type(2)));

#define BROWS 2048
#define NCOLS 8192
#define KSTEPS 64

#define THREADS 256
#define EPT (NCOLS / THREADS)  // 32 elements per thread
#define NPAIR (EPT / 2)        // 16 fp16 pairs for kh
#define NWAVE (THREADS / 64)   // 4

__device__ __forceinline__ float wave_sum_dpp(float x) {
    int t;
    t = __builtin_amdgcn_update_dpp(0, __builtin_bit_cast(int, x), 0x111, 0xf, 0xf, true);  // row_shr:1
    x += __builtin_bit_cast(float, t);
    t = __builtin_amdgcn_update_dpp(0, __builtin_bit_cast(int, x), 0x112, 0xf, 0xf, true);  // row_shr:2
    x += __builtin_bit_cast(float, t);
    t = __builtin_amdgcn_update_dpp(0, __builtin_bit_cast(int, x), 0x114, 0xf, 0xf, true);  // row_shr:4
    x += __builtin_bit_cast(float, t);
    t = __builtin_amdgcn_update_dpp(0, __builtin_bit_cast(int, x), 0x118, 0xf, 0xf, true);  // row_shr:8
    x += __builtin_bit_cast(float, t);
    // lanes 15/31/47/63 hold their 16-lane row sums
    t = __builtin_amdgcn_update_dpp(0, __builtin_bit_cast(int, x), 0x142, 0xa, 0xf, false); // row_bcast:15 -> rows 1,3
    x += __builtin_bit_cast(float, t);
    t = __builtin_amdgcn_update_dpp(0, __builtin_bit_cast(int, x), 0x143, 0xc, 0xf, false); // row_bcast:31 -> rows 2,3
    x += __builtin_bit_cast(float, t);
    return __builtin_bit_cast(float, __builtin_amdgcn_readlane(__builtin_bit_cast(int, x), 63));
}

__global__ __launch_bounds__(THREADS, 5) void gumbel_subset_kernel(
    const float* __restrict__ scores,
    const float* __restrict__ g,
    float* __restrict__ out)
{
    const int row = blockIdx.x;
    const int t = threadIdx.x;
    const float* __restrict__ srow = scores + (size_t)row * NCOLS;
    const float* __restrict__ grow = g + (size_t)row * NCOLS;
    float* __restrict__ orow = out + (size_t)row * NCOLS;

    __shared__ float red[2][NWAVE]; // double-buffered per-wave partials
    const int wave = t >> 6;
    const int lane = t & 63;

    // ---- pass 1: stream s0 = scores + g, track max ONLY (no staging) ----
    float m = -INFINITY;
#pragma unroll
    for (int c = 0; c < EPT / 4; ++c) {
        const int idx = c * (THREADS * 4) + t * 4;
        const float4 a = *reinterpret_cast<const float4*>(srow + idx);
        const float4 b = *reinterpret_cast<const float4*>(grow + idx);
        m = fmaxf(m, fmaxf(fmaxf(a.x + b.x, a.y + b.y),
                           fmaxf(a.z + b.z, a.w + b.w)));
    }

    // ---- block max reduction (shfl path, proven) ----
#pragma unroll
    for (int off = 32; off > 0; off >>= 1)
        m = fmaxf(m, __shfl_xor(m, off, 64));
    if (lane == 0) red[0][wave] = m;
    __syncthreads();
    m = fmaxf(fmaxf(red[0][0], red[0][1]), fmaxf(red[0][2], red[0][3]));
    __syncthreads(); // red[0] is re-written by iteration 0 below

    // ---- pass 2: reload (L2/L3-hot), v = exp(s0-m) f32, kh = 0 fp16 ----
    float v[EPT];
    h2 kh[NPAIR];
    float sa = 0.0f, sb = 0.0f, sc = 0.0f, sd = 0.0f;
#pragma unroll
    for (int c = 0; c < EPT / 4; ++c) {
        const int idx = c * (THREADS * 4) + t * 4;
        const float4 a = *reinterpret_cast<const float4*>(srow + idx);
        const float4 b = *reinterpret_cast<const float4*>(grow + idx);
        v[c * 4 + 0] = __expf(a.x + b.x - m);
        v[c * 4 + 1] = __expf(a.y + b.y - m);
        v[c * 4 + 2] = __expf(a.z + b.z - m);
        v[c * 4 + 3] = __expf(a.w + b.w - m);
        kh[2 * c + 0] = (h2){(_Float16)0.0f, (_Float16)0.0f};
        kh[2 * c + 1] = (h2){(_Float16)0.0f, (_Float16)0.0f};
        sa += v[c * 4 + 0]; sb += v[c * 4 + 1];
        sc += v[c * 4 + 2]; sd += v[c * 4 + 3];
    }

    // ---- K relaxation steps ----
#pragma unroll 2
    for (int it = 0; it < KSTEPS; ++it) {
        const float s = wave_sum_dpp((sa + sb) + (sc + sd));

        const int buf = it & 1;
        if (lane == 0) red[buf][wave] = s;
        __syncthreads();
        const float S = (red[buf][0] + red[buf][1]) + (red[buf][2] + red[buf][3]);
        const float rinv = __builtin_amdgcn_rcpf(S);

        sa = 0.0f; sb = 0.0f; sc = 0.0f; sd = 0.0f;
#pragma unroll
        for (int q = 0; q < NPAIR; q += 2) {
            // pair q: elems 2q, 2q+1
            {
                const float w0 = v[2 * q + 0] * rinv;
                const float w1 = v[2 * q + 1] * rinv;
                h2 pkw, kn;
                asm("v_cvt_pkrtz_f16_f32 %0, %1, %2" : "=&v"(pkw) : "v"(w0), "v"(w1));
                asm("v_pk_add_f16 %0, %1, %2" : "=&v"(kn) : "v"(kh[q]), "v"(pkw));
                kh[q] = kn;
                v[2 * q + 0] = __builtin_fmaf(-w0, v[2 * q + 0], v[2 * q + 0]);
                v[2 * q + 1] = __builtin_fmaf(-w1, v[2 * q + 1], v[2 * q + 1]);
                sa += v[2 * q + 0]; sb += v[2 * q + 1];
            }
            {
                const float w0 = v[2 * q + 2] * rinv;
                const float w1 = v[2 * q + 3] * rinv;
                h2 pkw, kn;
                asm("v_cvt_pkrtz_f16_f32 %0, %1, %2" : "=&v"(pkw) : "v"(w0), "v"(w1));
                asm("v_pk_add_f16 %0, %1, %2" : "=&v"(kn) : "v"(kh[q + 1]), "v"(pkw));
                kh[q + 1] = kn;
                v[2 * q + 2] = __builtin_fmaf(-w0, v[2 * q + 2], v[2 * q + 2]);
                v[2 * q + 3] = __builtin_fmaf(-w1, v[2 * q + 3], v[2 * q + 3]);
                sc += v[2 * q + 2]; sd += v[2 * q + 3];
            }
        }
        // single barrier per iteration: next write targets the other buffer;
        // this buffer is only re-written after the *next* barrier.
    }

    // ---- store khot (coalesced float4; pairs 2c, 2c+1 -> lanes xyzw) ----
#pragma unroll
    for (int c = 0; c < EPT / 4; ++c) {
        const int idx = c * (THREADS * 4) + t * 4;
        float4 o;
        o.x = (float)kh[2 * c + 0].x;
        o.y = (float)kh[2 * c + 0].y;
        o.z = (float)kh[2 * c + 1].x;
        o.w = (float)kh[2 * c + 1].y;
        *reinterpret_cast<float4*>(orow + idx) = o;
    }
}

extern "C" void kernel_launch(void* const* d_in, const int* in_sizes, int n_in,
                              void* d_out, int out_size, void* d_ws, size_t ws_size,
                              hipStream_t stream) {
    const float* scores = (const float*)d_in[0];
    const float* g = (const float*)d_in[1];
    float* out = (float*)d_out;
    (void)in_sizes; (void)n_in; (void)out_size; (void)d_ws; (void)ws_size;

    gumbel_subset_kernel<<<BROWS, THREADS, 0, stream>>>(scores, g, out);
}

// Round 16
// 110.518 us; speedup vs baseline: 1.0567x; 1.0567x over previous
//
#include <hip/hip_runtime.h>
#include <math.h>

// Gumbel subset (relaxed top-k) — B=2048 rows, N=8192, K=64 softmax steps.
// Multiplicative reformulation: v_i = exp(s0_i - M0), per step:
//   w = v*rinv(S); kh += w; v = fma(-w, v, v); part' = sum(v).
// R16: R14 (best, 101.1us) + ONE change: kh in packed fp16 via the R15-
// proven cvt_pkrtz + v_pk_add_f16 pair (same op count as 2 f32 adds,
// absmax 0.031 validated twice). One-pass prologue kept (R15's two-pass
// reload cost +40MB HBM and +14us busy - reverted). State 64->48 floats;
// total footprint ~180->~130 regs -> ~4 waves/SIMD to cover R14's 33us
// idle. DPP wave-reduce + double-buffered LDS partials unchanged.

typedef _Float16 h2 __attribute__((ext_vector_type(2)));

#define BROWS 2048
#define NCOLS 8192
#define KSTEPS 64

#define THREADS 256
#define EPT (NCOLS / THREADS)  // 32 elements per thread
#define NPAIR (EPT / 2)        // 16 fp16 pairs for kh
#define NWAVE (THREADS / 64)   // 4

__device__ __forceinline__ float wave_sum_dpp(float x) {
    int t;
    t = __builtin_amdgcn_update_dpp(0, __builtin_bit_cast(int, x), 0x111, 0xf, 0xf, true);  // row_shr:1
    x += __builtin_bit_cast(float, t);
    t = __builtin_amdgcn_update_dpp(0, __builtin_bit_cast(int, x), 0x112, 0xf, 0xf, true);  // row_shr:2
    x += __builtin_bit_cast(float, t);
    t = __builtin_amdgcn_update_dpp(0, __builtin_bit_cast(int, x), 0x114, 0xf, 0xf, true);  // row_shr:4
    x += __builtin_bit_cast(float, t);
    t = __builtin_amdgcn_update_dpp(0, __builtin_bit_cast(int, x), 0x118, 0xf, 0xf, true);  // row_shr:8
    x += __builtin_bit_cast(float, t);
    // lanes 15/31/47/63 hold their 16-lane row sums
    t = __builtin_amdgcn_update_dpp(0, __builtin_bit_cast(int, x), 0x142, 0xa, 0xf, false); // row_bcast:15 -> rows 1,3
    x += __builtin_bit_cast(float, t);
    t = __builtin_amdgcn_update_dpp(0, __builtin_bit_cast(int, x), 0x143, 0xc, 0xf, false); // row_bcast:31 -> rows 2,3
    x += __builtin_bit_cast(float, t);
    return __builtin_bit_cast(float, __builtin_amdgcn_readlane(__builtin_bit_cast(int, x), 63));
}

__global__ __launch_bounds__(THREADS, 2) void gumbel_subset_kernel(
    const float* __restrict__ scores,
    const float* __restrict__ g,
    float* __restrict__ out)
{
    const int row = blockIdx.x;
    const int t = threadIdx.x;
    const float* __restrict__ srow = scores + (size_t)row * NCOLS;
    const float* __restrict__ grow = g + (size_t)row * NCOLS;
    float* __restrict__ orow = out + (size_t)row * NCOLS;

    float v[EPT];    // s0 staging, then softmax weights (f32)
    h2 kh[NPAIR];    // khot accumulator (packed fp16)

    // ---- load s0 = scores + g (coalesced float4), track local max ----
    float m = -INFINITY;
#pragma unroll
    for (int c = 0; c < EPT / 4; ++c) {
        const int idx = c * (THREADS * 4) + t * 4;
        const float4 a = *reinterpret_cast<const float4*>(srow + idx);
        const float4 b = *reinterpret_cast<const float4*>(grow + idx);
        const float s0 = a.x + b.x;
        const float s1 = a.y + b.y;
        const float s2 = a.z + b.z;
        const float s3 = a.w + b.w;
        v[c * 4 + 0] = s0;
        v[c * 4 + 1] = s1;
        v[c * 4 + 2] = s2;
        v[c * 4 + 3] = s3;
        m = fmaxf(m, fmaxf(fmaxf(s0, s1), fmaxf(s2, s3)));
    }

    __shared__ float red[2][NWAVE]; // double-buffered per-wave partials
    const int wave = t >> 6;
    const int lane = t & 63;

    // ---- block max reduction (once; shfl path, proven) ----
#pragma unroll
    for (int off = 32; off > 0; off >>= 1)
        m = fmaxf(m, __shfl_xor(m, off, 64));
    if (lane == 0) red[0][wave] = m;
    __syncthreads();
    m = fmaxf(fmaxf(red[0][0], red[0][1]), fmaxf(red[0][2], red[0][3]));
    __syncthreads(); // red[0] is re-written by iteration 0 below

    // ---- v = exp(s0 - M0), kh = 0 (fp16), initial partial sums ----
    float sa = 0.0f, sb = 0.0f, sc = 0.0f, sd = 0.0f;
#pragma unroll
    for (int e = 0; e < EPT; e += 4) {
        v[e + 0] = __expf(v[e + 0] - m);
        v[e + 1] = __expf(v[e + 1] - m);
        v[e + 2] = __expf(v[e + 2] - m);
        v[e + 3] = __expf(v[e + 3] - m);
        kh[e / 2 + 0] = (h2){(_Float16)0.0f, (_Float16)0.0f};
        kh[e / 2 + 1] = (h2){(_Float16)0.0f, (_Float16)0.0f};
        sa += v[e + 0]; sb += v[e + 1]; sc += v[e + 2]; sd += v[e + 3];
    }

    // ---- K relaxation steps ----
#pragma unroll 2
    for (int it = 0; it < KSTEPS; ++it) {
        const float s = wave_sum_dpp((sa + sb) + (sc + sd));

        const int buf = it & 1;
        if (lane == 0) red[buf][wave] = s;
        __syncthreads();
        const float S = (red[buf][0] + red[buf][1]) + (red[buf][2] + red[buf][3]);
        const float rinv = __builtin_amdgcn_rcpf(S);

        sa = 0.0f; sb = 0.0f; sc = 0.0f; sd = 0.0f;
#pragma unroll
        for (int q = 0; q < NPAIR; q += 2) {
            {
                const float w0 = v[2 * q + 0] * rinv;
                const float w1 = v[2 * q + 1] * rinv;
                h2 pkw, kn;
                asm("v_cvt_pkrtz_f16_f32 %0, %1, %2" : "=&v"(pkw) : "v"(w0), "v"(w1));
                asm("v_pk_add_f16 %0, %1, %2" : "=&v"(kn) : "v"(kh[q]), "v"(pkw));
                kh[q] = kn;
                v[2 * q + 0] = __builtin_fmaf(-w0, v[2 * q + 0], v[2 * q + 0]);
                v[2 * q + 1] = __builtin_fmaf(-w1, v[2 * q + 1], v[2 * q + 1]);
                sa += v[2 * q + 0]; sb += v[2 * q + 1];
            }
            {
                const float w0 = v[2 * q + 2] * rinv;
                const float w1 = v[2 * q + 3] * rinv;
                h2 pkw, kn;
                asm("v_cvt_pkrtz_f16_f32 %0, %1, %2" : "=&v"(pkw) : "v"(w0), "v"(w1));
                asm("v_pk_add_f16 %0, %1, %2" : "=&v"(kn) : "v"(kh[q + 1]), "v"(pkw));
                kh[q + 1] = kn;
                v[2 * q + 2] = __builtin_fmaf(-w0, v[2 * q + 2], v[2 * q + 2]);
                v[2 * q + 3] = __builtin_fmaf(-w1, v[2 * q + 3], v[2 * q + 3]);
                sc += v[2 * q + 2]; sd += v[2 * q + 3];
            }
        }
        // single barrier per iteration: next write targets the other buffer;
        // this buffer is only re-written after the *next* barrier.
    }

    // ---- store khot (coalesced float4; pairs 2c, 2c+1 -> lanes xyzw) ----
#pragma unroll
    for (int c = 0; c < EPT / 4; ++c) {
        const int idx = c * (THREADS * 4) + t * 4;
        float4 o;
        o.x = (float)kh[2 * c + 0].x;
        o.y = (float)kh[2 * c + 0].y;
        o.z = (float)kh[2 * c + 1].x;
        o.w = (float)kh[2 * c + 1].y;
        *reinterpret_cast<float4*>(orow + idx) = o;
    }
}

extern "C" void kernel_launch(void* const* d_in, const int* in_sizes, int n_in,
                              void* d_out, int out_size, void* d_ws, size_t ws_size,
                              hipStream_t stream) {
    const float* scores = (const float*)d_in[0];
    const float* g = (const float*)d_in[1];
    float* out = (float*)d_out;
    (void)in_sizes; (void)n_in; (void)out_size; (void)d_ws; (void)ws_size;

    gumbel_subset_kernel<<<BROWS, THREADS, 0, stream>>>(scores, g, out);
}

// Round 17
// 102.044 us; speedup vs baseline: 1.1445x; 1.0830x over previous
//
#include <hip/hip_runtime.h>
#include <math.h>

// Gumbel subset (relaxed top-k) — B=2048 rows, N=8192, K=64 softmax steps.
// Multiplicative reformulation: v_i = exp(s0_i - M0), per step:
//   w = v*rinv(S); kh += w; v = fma(-w, v, v).
// R17: HALVE THE BARRIER FREQUENCY via analytic S propagation.
//   v' = v - v^2/S  =>  S' = S - Q/S,  Q = sum(v^2)  (exact in f32).
// Each superstep (2 iters): one cross-wave reduction of (s1,s2)=(sum v,
// sum v^2) gives S_t (exact) and S_{t+1} = S_t - Q_t/S_t (analytic, drift
// re-corrected every reduction). 32 barriers instead of 64; reduce
// machinery halves; fused 2-iter update is 9 ops/elem vs 8.
// R14's proven parts kept: one-pass prologue, DPP wave reduce (dual
// interleaved chains), double-buffered LDS partials, pure-C f32 loop
// (R10/R12/R16: asm on persistent state = AGPR mov tax - banned).

#define BROWS 2048
#define NCOLS 8192
#define KSTEPS 64
#define NSUPER (KSTEPS / 2)    // 32 supersteps

#define THREADS 256
#define EPT (NCOLS / THREADS)  // 32
#define NWAVE (THREADS / 64)   // 4

// Dual 64-lane sum via two interleaved DPP chains; returns {sum_x, sum_y}.
__device__ __forceinline__ float2 wave_sum2_dpp(float x, float y) {
    int tx, ty;
    tx = __builtin_amdgcn_update_dpp(0, __builtin_bit_cast(int, x), 0x111, 0xf, 0xf, true);
    ty = __builtin_amdgcn_update_dpp(0, __builtin_bit_cast(int, y), 0x111, 0xf, 0xf, true);
    x += __builtin_bit_cast(float, tx);
    y += __builtin_bit_cast(float, ty);
    tx = __builtin_amdgcn_update_dpp(0, __builtin_bit_cast(int, x), 0x112, 0xf, 0xf, true);
    ty = __builtin_amdgcn_update_dpp(0, __builtin_bit_cast(int, y), 0x112, 0xf, 0xf, true);
    x += __builtin_bit_cast(float, tx);
    y += __builtin_bit_cast(float, ty);
    tx = __builtin_amdgcn_update_dpp(0, __builtin_bit_cast(int, x), 0x114, 0xf, 0xf, true);
    ty = __builtin_amdgcn_update_dpp(0, __builtin_bit_cast(int, y), 0x114, 0xf, 0xf, true);
    x += __builtin_bit_cast(float, tx);
    y += __builtin_bit_cast(float, ty);
    tx = __builtin_amdgcn_update_dpp(0, __builtin_bit_cast(int, x), 0x118, 0xf, 0xf, true);
    ty = __builtin_amdgcn_update_dpp(0, __builtin_bit_cast(int, y), 0x118, 0xf, 0xf, true);
    x += __builtin_bit_cast(float, tx);
    y += __builtin_bit_cast(float, ty);
    // lanes 15/31/47/63 hold 16-lane row sums
    tx = __builtin_amdgcn_update_dpp(0, __builtin_bit_cast(int, x), 0x142, 0xa, 0xf, false);
    ty = __builtin_amdgcn_update_dpp(0, __builtin_bit_cast(int, y), 0x142, 0xa, 0xf, false);
    x += __builtin_bit_cast(float, tx);
    y += __builtin_bit_cast(float, ty);
    tx = __builtin_amdgcn_update_dpp(0, __builtin_bit_cast(int, x), 0x143, 0xc, 0xf, false);
    ty = __builtin_amdgcn_update_dpp(0, __builtin_bit_cast(int, y), 0x143, 0xc, 0xf, false);
    x += __builtin_bit_cast(float, tx);
    y += __builtin_bit_cast(float, ty);
    float2 r;
    r.x = __builtin_bit_cast(float, __builtin_amdgcn_readlane(__builtin_bit_cast(int, x), 63));
    r.y = __builtin_bit_cast(float, __builtin_amdgcn_readlane(__builtin_bit_cast(int, y), 63));
    return r;
}

__global__ __launch_bounds__(THREADS, 2) void gumbel_subset_kernel(
    const float* __restrict__ scores,
    const float* __restrict__ g,
    float* __restrict__ out)
{
    const int row = blockIdx.x;
    const int t = threadIdx.x;
    const float* __restrict__ srow = scores + (size_t)row * NCOLS;
    const float* __restrict__ grow = g + (size_t)row * NCOLS;
    float* __restrict__ orow = out + (size_t)row * NCOLS;

    float v[EPT];
    float kh[EPT];

    // ---- load s0 = scores + g (coalesced float4), track local max ----
    float m = -INFINITY;
#pragma unroll
    for (int c = 0; c < EPT / 4; ++c) {
        const int idx = c * (THREADS * 4) + t * 4;
        const float4 a = *reinterpret_cast<const float4*>(srow + idx);
        const float4 b = *reinterpret_cast<const float4*>(grow + idx);
        const float s0 = a.x + b.x;
        const float s1 = a.y + b.y;
        const float s2 = a.z + b.z;
        const float s3 = a.w + b.w;
        v[c * 4 + 0] = s0;
        v[c * 4 + 1] = s1;
        v[c * 4 + 2] = s2;
        v[c * 4 + 3] = s3;
        m = fmaxf(m, fmaxf(fmaxf(s0, s1), fmaxf(s2, s3)));
    }

    __shared__ float redm[NWAVE];       // prologue max partials
    __shared__ float2 red[2][NWAVE];    // double-buffered (s1,s2) partials
    const int wave = t >> 6;
    const int lane = t & 63;

    // ---- block max reduction (once; shfl path, proven) ----
#pragma unroll
    for (int off = 32; off > 0; off >>= 1)
        m = fmaxf(m, __shfl_xor(m, off, 64));
    if (lane == 0) redm[wave] = m;
    __syncthreads();
    m = fmaxf(fmaxf(redm[0], redm[1]), fmaxf(redm[2], redm[3]));

    // ---- v = exp(s0 - M0), kh = 0, initial (sum, sumsq) partials ----
    float sa = 0.0f, sb = 0.0f, sc = 0.0f, sd = 0.0f;   // sum v
    float qa = 0.0f, qb = 0.0f, qc = 0.0f, qd = 0.0f;   // sum v^2
#pragma unroll
    for (int e = 0; e < EPT; e += 4) {
        v[e + 0] = __expf(v[e + 0] - m);
        v[e + 1] = __expf(v[e + 1] - m);
        v[e + 2] = __expf(v[e + 2] - m);
        v[e + 3] = __expf(v[e + 3] - m);
        kh[e + 0] = 0.0f; kh[e + 1] = 0.0f; kh[e + 2] = 0.0f; kh[e + 3] = 0.0f;
        sa += v[e + 0]; sb += v[e + 1]; sc += v[e + 2]; sd += v[e + 3];
        qa = __builtin_fmaf(v[e + 0], v[e + 0], qa);
        qb = __builtin_fmaf(v[e + 1], v[e + 1], qb);
        qc = __builtin_fmaf(v[e + 2], v[e + 2], qc);
        qd = __builtin_fmaf(v[e + 3], v[e + 3], qd);
    }
    __syncthreads(); // redm read done before red[] reuse... (separate arrays; fences prologue)

    // ---- 32 supersteps of 2 relaxation iterations each ----
    for (int k = 0; k < NSUPER; ++k) {
        const float2 p = wave_sum2_dpp((sa + sb) + (sc + sd),
                                       (qa + qb) + (qc + qd));

        const int buf = k & 1;
        if (lane == 0) red[buf][wave] = p;
        __syncthreads();
        const float2 r0 = red[buf][0];
        const float2 r1 = red[buf][1];
        const float2 r2 = red[buf][2];
        const float2 r3 = red[buf][3];
        const float S1 = (r0.x + r1.x) + (r2.x + r3.x);   // sum v (exact)
        const float Q1 = (r0.y + r1.y) + (r2.y + r3.y);   // sum v^2
        const float ri1 = __builtin_amdgcn_rcpf(S1);
        const float S2 = __builtin_fmaf(-Q1, ri1, S1);    // S' = S - Q/S (exact identity)
        const float ri2 = __builtin_amdgcn_rcpf(S2);

        sa = 0.0f; sb = 0.0f; sc = 0.0f; sd = 0.0f;
        qa = 0.0f; qb = 0.0f; qc = 0.0f; qd = 0.0f;
#pragma unroll
        for (int e = 0; e < EPT; e += 4) {
            // iter A (denominator S1)
            const float wA0 = v[e + 0] * ri1;
            const float wA1 = v[e + 1] * ri1;
            const float wA2 = v[e + 2] * ri1;
            const float wA3 = v[e + 3] * ri1;
            kh[e + 0] += wA0; kh[e + 1] += wA1; kh[e + 2] += wA2; kh[e + 3] += wA3;
            v[e + 0] = __builtin_fmaf(-wA0, v[e + 0], v[e + 0]);
            v[e + 1] = __builtin_fmaf(-wA1, v[e + 1], v[e + 1]);
            v[e + 2] = __builtin_fmaf(-wA2, v[e + 2], v[e + 2]);
            v[e + 3] = __builtin_fmaf(-wA3, v[e + 3], v[e + 3]);
            // iter B (denominator S2, analytic)
            const float wB0 = v[e + 0] * ri2;
            const float wB1 = v[e + 1] * ri2;
            const float wB2 = v[e + 2] * ri2;
            const float wB3 = v[e + 3] * ri2;
            kh[e + 0] += wB0; kh[e + 1] += wB1; kh[e + 2] += wB2; kh[e + 3] += wB3;
            v[e + 0] = __builtin_fmaf(-wB0, v[e + 0], v[e + 0]);
            v[e + 1] = __builtin_fmaf(-wB1, v[e + 1], v[e + 1]);
            v[e + 2] = __builtin_fmaf(-wB2, v[e + 2], v[e + 2]);
            v[e + 3] = __builtin_fmaf(-wB3, v[e + 3], v[e + 3]);
            // next-superstep partials: sum v, sum v^2
            sa += v[e + 0]; sb += v[e + 1]; sc += v[e + 2]; sd += v[e + 3];
            qa = __builtin_fmaf(v[e + 0], v[e + 0], qa);
            qb = __builtin_fmaf(v[e + 1], v[e + 1], qb);
            qc = __builtin_fmaf(v[e + 2], v[e + 2], qc);
            qd = __builtin_fmaf(v[e + 3], v[e + 3], qd);
        }
        // single barrier per superstep: next write targets the other buffer;
        // this buffer is only re-written after the *next* barrier.
    }

    // ---- store khot (coalesced float4) ----
#pragma unroll
    for (int c = 0; c < EPT / 4; ++c) {
        const int idx = c * (THREADS * 4) + t * 4;
        float4 o;
        o.x = kh[c * 4 + 0];
        o.y = kh[c * 4 + 1];
        o.z = kh[c * 4 + 2];
        o.w = kh[c * 4 + 3];
        *reinterpret_cast<float4*>(orow + idx) = o;
    }
}

extern "C" void kernel_launch(void* const* d_in, const int* in_sizes, int n_in,
                              void* d_out, int out_size, void* d_ws, size_t ws_size,
                              hipStream_t stream) {
    const float* scores = (const float*)d_in[0];
    const float* g = (const float*)d_in[1];
    float* out = (float*)d_out;
    (void)in_sizes; (void)n_in; (void)out_size; (void)d_ws; (void)ws_size;

    gumbel_subset_kernel<<<BROWS, THREADS, 0, stream>>>(scores, g, out);
}

// Round 18
// 100.828 us; speedup vs baseline: 1.1583x; 1.0121x over previous
//
#include <hip/hip_runtime.h>
#include <math.h>

// Gumbel subset (relaxed top-k) — B=2048 rows, N=8192, K=64 softmax steps.
// Multiplicative reformulation: v_i = exp(s0_i - M0), per step:
//   w = v*rinv(S); kh += w; v = fma(-w, v, v); part' = sum(v).
// R18 (final): revert to R14 (best, 101.1us) + one free micro-fix: red[]
// is 16B-aligned and the per-iteration partial read is a single float4
// (ds_read_b128) instead of 4 scalar ds_read_b32.
// Settled findings across R1-R17:
//  - busy floor ~82us: issue-bound at scalar f32 rate; VOP3P (pk f32/f16)
//    is 2-pass on CDNA4 SIMD-32 -> packing never reduces VALU cycles.
//  - inline asm on persistent state forces AGPR<->VGPR movs (net loss).
//  - occupancy is state-bound (~3-4 waves/SIMD); reg caps spill (R13),
//    fp16 state + extra cvts cost more busy than the idle they recover.
//  - DPP wave-reduce (6 ops) beats shfl_xor chain (+8us win, R14).
//  - barrier halving (analytic S, R17) = wash (+Q fmas == saved machinery).

#define BROWS 2048
#define NCOLS 8192
#define KSTEPS 64

#define THREADS 256
#define EPT (NCOLS / THREADS)  // 32
#define NWAVE (THREADS / 64)   // 4

__device__ __forceinline__ float wave_sum_dpp(float x) {
    int t;
    t = __builtin_amdgcn_update_dpp(0, __builtin_bit_cast(int, x), 0x111, 0xf, 0xf, true);  // row_shr:1
    x += __builtin_bit_cast(float, t);
    t = __builtin_amdgcn_update_dpp(0, __builtin_bit_cast(int, x), 0x112, 0xf, 0xf, true);  // row_shr:2
    x += __builtin_bit_cast(float, t);
    t = __builtin_amdgcn_update_dpp(0, __builtin_bit_cast(int, x), 0x114, 0xf, 0xf, true);  // row_shr:4
    x += __builtin_bit_cast(float, t);
    t = __builtin_amdgcn_update_dpp(0, __builtin_bit_cast(int, x), 0x118, 0xf, 0xf, true);  // row_shr:8
    x += __builtin_bit_cast(float, t);
    // lanes 15/31/47/63 hold their 16-lane row sums
    t = __builtin_amdgcn_update_dpp(0, __builtin_bit_cast(int, x), 0x142, 0xa, 0xf, false); // row_bcast:15 -> rows 1,3
    x += __builtin_bit_cast(float, t);
    t = __builtin_amdgcn_update_dpp(0, __builtin_bit_cast(int, x), 0x143, 0xc, 0xf, false); // row_bcast:31 -> rows 2,3
    x += __builtin_bit_cast(float, t);
    return __builtin_bit_cast(float, __builtin_amdgcn_readlane(__builtin_bit_cast(int, x), 63));
}

__global__ __launch_bounds__(THREADS, 2) void gumbel_subset_kernel(
    const float* __restrict__ scores,
    const float* __restrict__ g,
    float* __restrict__ out)
{
    const int row = blockIdx.x;
    const int t = threadIdx.x;
    const float* __restrict__ srow = scores + (size_t)row * NCOLS;
    const float* __restrict__ grow = g + (size_t)row * NCOLS;
    float* __restrict__ orow = out + (size_t)row * NCOLS;

    float v[EPT];
    float kh[EPT];

    // ---- load s0 = scores + g (coalesced float4), track local max ----
    float m = -INFINITY;
#pragma unroll
    for (int c = 0; c < EPT / 4; ++c) {
        const int idx = c * (THREADS * 4) + t * 4;
        const float4 a = *reinterpret_cast<const float4*>(srow + idx);
        const float4 b = *reinterpret_cast<const float4*>(grow + idx);
        const float s0 = a.x + b.x;
        const float s1 = a.y + b.y;
        const float s2 = a.z + b.z;
        const float s3 = a.w + b.w;
        v[c * 4 + 0] = s0;
        v[c * 4 + 1] = s1;
        v[c * 4 + 2] = s2;
        v[c * 4 + 3] = s3;
        m = fmaxf(m, fmaxf(fmaxf(s0, s1), fmaxf(s2, s3)));
    }

    __shared__ __align__(16) float red[2][NWAVE]; // double-buffered per-wave partials
    const int wave = t >> 6;
    const int lane = t & 63;

    // ---- block max reduction (once; shfl path, proven) ----
#pragma unroll
    for (int off = 32; off > 0; off >>= 1)
        m = fmaxf(m, __shfl_xor(m, off, 64));
    if (lane == 0) red[0][wave] = m;
    __syncthreads();
    {
        const float4 r4 = *reinterpret_cast<const float4*>(&red[0][0]);
        m = fmaxf(fmaxf(r4.x, r4.y), fmaxf(r4.z, r4.w));
    }
    __syncthreads(); // red[0] is re-written by iteration 0 below

    // ---- v = exp(s0 - M0), khot = 0, initial partial sums ----
    float sa = 0.0f, sb = 0.0f, sc = 0.0f, sd = 0.0f;
#pragma unroll
    for (int e = 0; e < EPT; e += 4) {
        v[e + 0] = __expf(v[e + 0] - m);
        v[e + 1] = __expf(v[e + 1] - m);
        v[e + 2] = __expf(v[e + 2] - m);
        v[e + 3] = __expf(v[e + 3] - m);
        kh[e + 0] = 0.0f; kh[e + 1] = 0.0f; kh[e + 2] = 0.0f; kh[e + 3] = 0.0f;
        sa += v[e + 0]; sb += v[e + 1]; sc += v[e + 2]; sd += v[e + 3];
    }

    // ---- K relaxation steps ----
#pragma unroll 2
    for (int it = 0; it < KSTEPS; ++it) {
        const float s = wave_sum_dpp((sa + sb) + (sc + sd));

        const int buf = it & 1;
        if (lane == 0) red[buf][wave] = s;
        __syncthreads();
        const float4 r4 = *reinterpret_cast<const float4*>(&red[buf][0]);
        const float S = (r4.x + r4.y) + (r4.z + r4.w);
        const float rinv = __builtin_amdgcn_rcpf(S);

        sa = 0.0f; sb = 0.0f; sc = 0.0f; sd = 0.0f;
#pragma unroll
        for (int e = 0; e < EPT; e += 4) {
            const float w0 = v[e + 0] * rinv;
            const float w1 = v[e + 1] * rinv;
            const float w2 = v[e + 2] * rinv;
            const float w3 = v[e + 3] * rinv;
            kh[e + 0] += w0; kh[e + 1] += w1; kh[e + 2] += w2; kh[e + 3] += w3;
            v[e + 0] = __builtin_fmaf(-w0, v[e + 0], v[e + 0]);
            v[e + 1] = __builtin_fmaf(-w1, v[e + 1], v[e + 1]);
            v[e + 2] = __builtin_fmaf(-w2, v[e + 2], v[e + 2]);
            v[e + 3] = __builtin_fmaf(-w3, v[e + 3], v[e + 3]);
            sa += v[e + 0]; sb += v[e + 1]; sc += v[e + 2]; sd += v[e + 3];
        }
        // single barrier per iteration: next write targets the other buffer;
        // this buffer is only re-written after the *next* barrier.
    }

    // ---- store khot (coalesced float4) ----
#pragma unroll
    for (int c = 0; c < EPT / 4; ++c) {
        const int idx = c * (THREADS * 4) + t * 4;
        float4 o;
        o.x = kh[c * 4 + 0];
        o.y = kh[c * 4 + 1];
        o.z = kh[c * 4 + 2];
        o.w = kh[c * 4 + 3];
        *reinterpret_cast<float4*>(orow + idx) = o;
    }
}

extern "C" void kernel_launch(void* const* d_in, const int* in_sizes, int n_in,
                              void* d_out, int out_size, void* d_ws, size_t ws_size,
                              hipStream_t stream) {
    const float* scores = (const float*)d_in[0];
    const float* g = (const float*)d_in[1];
    float* out = (float*)d_out;
    (void)in_sizes; (void)n_in; (void)out_size; (void)d_ws; (void)ws_size;

    gumbel_subset_kernel<<<BROWS, THREADS, 0, stream>>>(scores, g, out);
}